// Round 1
// baseline (136.765 us; speedup 1.0000x reference)
//
#include <hip/hip_runtime.h>
#include <math.h>

#define D 128
#define EPS_NORM 1e-12f

// One wave (64 lanes) per row: inv_norm[row] = 1 / max(||z_row||_2, eps)
__global__ void inv_norm_kernel(const float* __restrict__ z,
                                float* __restrict__ inv_norm, int N) {
    int row  = blockIdx.x * (blockDim.x >> 6) + (threadIdx.x >> 6);
    int lane = threadIdx.x & 63;
    if (row >= N) return;
    float2 v = reinterpret_cast<const float2*>(z + (size_t)row * D)[lane];
    float s = v.x * v.x + v.y * v.y;
#pragma unroll
    for (int off = 32; off > 0; off >>= 1)
        s += __shfl_xor(s, off, 64);
    if (lane == 0)
        inv_norm[row] = 1.0f / fmaxf(sqrtf(s), EPS_NORM);
}

// Elementwise cos of the phase table (R*D elements, tiny)
__global__ void cos_kernel(const float* __restrict__ phase,
                           float* __restrict__ cos_tab, int n) {
    int i = blockIdx.x * blockDim.x + threadIdx.x;
    if (i < n) cos_tab[i] = cosf(phase[i]);
}

// One wave per edge: dot(z[src] * cos_tab[type], z[dst]) * inv_norm[src]*inv_norm[dst]
__global__ void edge_kernel(const float* __restrict__ z,
                            const float* __restrict__ inv_norm,
                            const float* __restrict__ cos_tab,
                            const int* __restrict__ edge_index,
                            const int* __restrict__ edge_type,
                            float* __restrict__ out, int E) {
    int wid    = (int)((blockIdx.x * blockDim.x + threadIdx.x) >> 6);
    int lane   = threadIdx.x & 63;
    int nwaves = (int)((gridDim.x * blockDim.x) >> 6);
    for (int e = wid; e < E; e += nwaves) {
        int src = edge_index[e];
        int dst = edge_index[E + e];
        int t   = edge_type[e];
        float2 zs = reinterpret_cast<const float2*>(z + (size_t)src * D)[lane];
        float2 zd = reinterpret_cast<const float2*>(z + (size_t)dst * D)[lane];
        float2 c  = reinterpret_cast<const float2*>(cos_tab + (size_t)t * D)[lane];
        float p = zs.x * c.x * zd.x + zs.y * c.y * zd.y;
#pragma unroll
        for (int off = 32; off > 0; off >>= 1)
            p += __shfl_xor(p, off, 64);
        if (lane == 0)
            out[e] = p * inv_norm[src] * inv_norm[dst];
    }
}

extern "C" void kernel_launch(void* const* d_in, const int* in_sizes, int n_in,
                              void* d_out, int out_size, void* d_ws, size_t ws_size,
                              hipStream_t stream) {
    const float* z          = (const float*)d_in[0];
    const int*   edge_index = (const int*)d_in[1];   // [2, E] int32 per harness
    const int*   edge_type  = (const int*)d_in[2];   // [E] int32 per harness
    const float* phase_rel  = (const float*)d_in[3]; // [R, D]

    float* out = (float*)d_out;

    const int N = in_sizes[0] / D;
    const int E = in_sizes[2];
    const int R = in_sizes[3] / D;

    // Workspace layout: inv_norm[N] (padded to 64), cos_tab[R*D]
    float* inv_norm = (float*)d_ws;
    float* cos_tab  = inv_norm + ((N + 63) & ~63);

    // 1) per-row inverse norms (4 waves/block -> 4 rows/block)
    inv_norm_kernel<<<(N + 3) / 4, 256, 0, stream>>>(z, inv_norm, N);

    // 2) cos table
    const int nphase = R * D;
    cos_kernel<<<(nphase + 255) / 256, 256, 0, stream>>>(phase_rel, cos_tab, nphase);

    // 3) edge dot products: 2048 blocks * 4 waves = 8192 waves in flight
    edge_kernel<<<2048, 256, 0, stream>>>(z, inv_norm, cos_tab,
                                          edge_index, edge_type, out, E);
}

// Round 2
// 72.057 us; speedup vs baseline: 1.8980x; 1.8980x over previous
//
#include <hip/hip_runtime.h>
#include <math.h>

#define D 128
#define EPS_NORM 1e-12f

// ---------- bf16 helpers (RNE, ignores NaN which our data can't produce) ----------
__device__ __forceinline__ unsigned short f32_to_bf16(float f) {
    unsigned int u = __float_as_uint(f);
    u = (u + 0x7FFFu + ((u >> 16) & 1u)) >> 16;
    return (unsigned short)u;
}
__device__ __forceinline__ float bf_lo(unsigned int w) { return __uint_as_float(w << 16); }
__device__ __forceinline__ float bf_hi(unsigned int w) { return __uint_as_float(w & 0xFFFF0000u); }

// ---------- precompute: normalized z packed to bf16, one wave per row ----------
__global__ void norm_pack_kernel(const float* __restrict__ z,
                                 unsigned int* __restrict__ zn, // [N, D/2] packed bf16x2
                                 int N) {
    int row  = blockIdx.x * (blockDim.x >> 6) + (threadIdx.x >> 6);
    int lane = threadIdx.x & 63;
    if (row >= N) return;
    float2 v = reinterpret_cast<const float2*>(z + (size_t)row * D)[lane];
    float s = v.x * v.x + v.y * v.y;
#pragma unroll
    for (int off = 32; off > 0; off >>= 1) s += __shfl_xor(s, off, 64);
    float inv = 1.0f / fmaxf(sqrtf(s), EPS_NORM);
    unsigned int w = ((unsigned int)f32_to_bf16(v.y * inv) << 16) | f32_to_bf16(v.x * inv);
    zn[(size_t)row * (D / 2) + lane] = w;
}

// ---------- cos table (f32, tiny, L2-resident) ----------
__global__ void cos_kernel(const float* __restrict__ phase,
                           float* __restrict__ cos_tab, int n) {
    int i = blockIdx.x * blockDim.x + threadIdx.x;
    if (i < n) cos_tab[i] = cosf(phase[i]);
}

// ---------- main: 16 lanes per edge, 4 edges per wave ----------
__global__ void edge_kernel_bf16(const unsigned int* __restrict__ zn, // [N, D/2]
                                 const float* __restrict__ cos_tab,   // [R, D]
                                 const int* __restrict__ edge_index,
                                 const int* __restrict__ edge_type,
                                 float* __restrict__ out, int E) {
    int tid     = (int)(blockIdx.x * blockDim.x + threadIdx.x);
    int gid     = tid >> 4;            // 16-lane group id = edge slot
    int l       = threadIdx.x & 15;    // sublane within group
    int ngroups = (int)((gridDim.x * blockDim.x) >> 4);
    for (int e = gid; e < E; e += ngroups) {
        int src = edge_index[e];
        int dst = edge_index[E + e];
        int t   = edge_type[e];
        // sublane l covers elements [l*8, l*8+8)
        uint4  sw = reinterpret_cast<const uint4*>(zn + (size_t)src * (D / 2))[l];
        uint4  dw = reinterpret_cast<const uint4*>(zn + (size_t)dst * (D / 2))[l];
        const float4* pc = reinterpret_cast<const float4*>(cos_tab + (size_t)t * D) + 2 * l;
        float4 c0 = pc[0];
        float4 c1 = pc[1];
        float p = 0.f;
        p = fmaf(bf_lo(sw.x) * c0.x, bf_lo(dw.x), p);
        p = fmaf(bf_hi(sw.x) * c0.y, bf_hi(dw.x), p);
        p = fmaf(bf_lo(sw.y) * c0.z, bf_lo(dw.y), p);
        p = fmaf(bf_hi(sw.y) * c0.w, bf_hi(dw.y), p);
        p = fmaf(bf_lo(sw.z) * c1.x, bf_lo(dw.z), p);
        p = fmaf(bf_hi(sw.z) * c1.y, bf_hi(dw.z), p);
        p = fmaf(bf_lo(sw.w) * c1.z, bf_lo(dw.w), p);
        p = fmaf(bf_hi(sw.w) * c1.w, bf_hi(dw.w), p);
#pragma unroll
        for (int off = 8; off > 0; off >>= 1) p += __shfl_xor(p, off, 64);
        if (l == 0) out[e] = p;
    }
}

// ---------- fallback path (if ws too small for bf16 table): round-1 style ----------
__global__ void inv_norm_kernel(const float* __restrict__ z,
                                float* __restrict__ inv_norm, int N) {
    int row  = blockIdx.x * (blockDim.x >> 6) + (threadIdx.x >> 6);
    int lane = threadIdx.x & 63;
    if (row >= N) return;
    float2 v = reinterpret_cast<const float2*>(z + (size_t)row * D)[lane];
    float s = v.x * v.x + v.y * v.y;
#pragma unroll
    for (int off = 32; off > 0; off >>= 1) s += __shfl_xor(s, off, 64);
    if (lane == 0) inv_norm[row] = 1.0f / fmaxf(sqrtf(s), EPS_NORM);
}

__global__ void edge_kernel_f32(const float* __restrict__ z,
                                const float* __restrict__ inv_norm,
                                const float* __restrict__ cos_tab,
                                const int* __restrict__ edge_index,
                                const int* __restrict__ edge_type,
                                float* __restrict__ out, int E) {
    int wid    = (int)((blockIdx.x * blockDim.x + threadIdx.x) >> 6);
    int lane   = threadIdx.x & 63;
    int nwaves = (int)((gridDim.x * blockDim.x) >> 6);
    for (int e = wid; e < E; e += nwaves) {
        int src = edge_index[e];
        int dst = edge_index[E + e];
        int t   = edge_type[e];
        float2 zs = reinterpret_cast<const float2*>(z + (size_t)src * D)[lane];
        float2 zd = reinterpret_cast<const float2*>(z + (size_t)dst * D)[lane];
        float2 c  = reinterpret_cast<const float2*>(cos_tab + (size_t)t * D)[lane];
        float p = zs.x * c.x * zd.x + zs.y * c.y * zd.y;
#pragma unroll
        for (int off = 32; off > 0; off >>= 1) p += __shfl_xor(p, off, 64);
        if (lane == 0) out[e] = p * inv_norm[src] * inv_norm[dst];
    }
}

extern "C" void kernel_launch(void* const* d_in, const int* in_sizes, int n_in,
                              void* d_out, int out_size, void* d_ws, size_t ws_size,
                              hipStream_t stream) {
    const float* z          = (const float*)d_in[0];
    const int*   edge_index = (const int*)d_in[1];   // [2, E] int32 per harness
    const int*   edge_type  = (const int*)d_in[2];   // [E] int32 per harness
    const float* phase_rel  = (const float*)d_in[3]; // [R, D]
    float* out = (float*)d_out;

    const int N = in_sizes[0] / D;
    const int E = in_sizes[2];
    const int nphase = in_sizes[3]; // R * D

    const size_t zn_bytes  = (size_t)N * (D / 2) * sizeof(unsigned int); // 25.6 MB
    const size_t cos_bytes = (size_t)nphase * sizeof(float);             // 320 KB

    if (ws_size >= zn_bytes + cos_bytes) {
        unsigned int* zn = (unsigned int*)d_ws;
        float* cos_tab   = (float*)((char*)d_ws + zn_bytes);

        norm_pack_kernel<<<(N + 3) / 4, 256, 0, stream>>>(z, zn, N);
        cos_kernel<<<(nphase + 255) / 256, 256, 0, stream>>>(phase_rel, cos_tab, nphase);
        // 2048 blocks * 4 waves * 4 edges/wave = 32768 edge slots, grid-stride
        edge_kernel_bf16<<<2048, 256, 0, stream>>>(zn, cos_tab, edge_index, edge_type, out, E);
    } else {
        float* inv_norm = (float*)d_ws;
        float* cos_tab  = inv_norm + ((N + 63) & ~63);

        inv_norm_kernel<<<(N + 3) / 4, 256, 0, stream>>>(z, inv_norm, N);
        cos_kernel<<<(nphase + 255) / 256, 256, 0, stream>>>(phase_rel, cos_tab, nphase);
        edge_kernel_f32<<<2048, 256, 0, stream>>>(z, inv_norm, cos_tab,
                                                  edge_index, edge_type, out, E);
    }
}

// Round 3
// 63.180 us; speedup vs baseline: 2.1647x; 1.1405x over previous
//
#include <hip/hip_runtime.h>
#include <math.h>

#define D 128
#define EPS_NORM 1e-12f

__device__ __forceinline__ unsigned int f32_to_bf16(float f) {
    unsigned int u = __float_as_uint(f);
    return (u + 0x7FFFu + ((u >> 16) & 1u)) >> 16;
}
__device__ __forceinline__ float bf_lo(unsigned int w) { return __uint_as_float(w << 16); }
__device__ __forceinline__ float bf_hi(unsigned int w) { return __uint_as_float(w & 0xFFFF0000u); }

// 2 rows per wave: lanes 0-31 -> row 2w, lanes 32-63 -> row 2w+1, float4/lane.
__global__ void norm_pack_kernel(const float* __restrict__ z,
                                 unsigned int* __restrict__ zn, int N) {
    int w    = blockIdx.x * (blockDim.x >> 6) + (threadIdx.x >> 6);
    int lane = threadIdx.x & 63;
    int half = lane >> 5;
    int hl   = lane & 31;
    int row  = w * 2 + half;
    if (row >= N) return;
    float4 v = reinterpret_cast<const float4*>(z + (size_t)row * D)[hl];
    float s = v.x * v.x + v.y * v.y + v.z * v.z + v.w * v.w;
#pragma unroll
    for (int off = 16; off > 0; off >>= 1) s += __shfl_xor(s, off, 32);
    float inv = 1.0f / fmaxf(sqrtf(s), EPS_NORM);
    uint2 o;
    o.x = (f32_to_bf16(v.y * inv) << 16) | f32_to_bf16(v.x * inv);
    o.y = (f32_to_bf16(v.w * inv) << 16) | f32_to_bf16(v.z * inv);
    reinterpret_cast<uint2*>(zn + (size_t)row * (D / 2))[hl] = o;
}

// cos of phase table, packed bf16x2 (row-major [R, D/2] uints)
__global__ void cos_pack_kernel(const float* __restrict__ phase,
                                unsigned int* __restrict__ ct, int n2) {
    int i = blockIdx.x * blockDim.x + threadIdx.x;
    if (i < n2) {
        float a = cosf(phase[2 * i]);
        float b = cosf(phase[2 * i + 1]);
        ct[i] = (f32_to_bf16(b) << 16) | f32_to_bf16(a);
    }
}

__device__ __forceinline__ float dot8(uint4 sw, uint4 cw, uint4 dw) {
    float p;
    p = bf_lo(sw.x) * bf_lo(cw.x) * bf_lo(dw.x);
    p = fmaf(bf_hi(sw.x) * bf_hi(cw.x), bf_hi(dw.x), p);
    p = fmaf(bf_lo(sw.y) * bf_lo(cw.y), bf_lo(dw.y), p);
    p = fmaf(bf_hi(sw.y) * bf_hi(cw.y), bf_hi(dw.y), p);
    p = fmaf(bf_lo(sw.z) * bf_lo(cw.z), bf_lo(dw.z), p);
    p = fmaf(bf_hi(sw.z) * bf_hi(cw.z), bf_hi(dw.z), p);
    p = fmaf(bf_lo(sw.w) * bf_lo(cw.w), bf_lo(dw.w), p);
    p = fmaf(bf_hi(sw.w) * bf_hi(cw.w), bf_hi(dw.w), p);
    return p;
}

// 16 lanes per edge, 2 edges per group-iteration (all 6 gathers in flight).
__global__ __launch_bounds__(256, 8) void edge_kernel_v3(
    const unsigned int* __restrict__ zn,   // [N, D/2]
    const unsigned int* __restrict__ ct,   // [R, D/2]
    const int* __restrict__ edge_index,
    const int* __restrict__ edge_type,
    float* __restrict__ out, int E) {
    int tid     = (int)(blockIdx.x * blockDim.x + threadIdx.x);
    int gid     = tid >> 4;
    int l       = threadIdx.x & 15;
    int ngroups = (int)((gridDim.x * blockDim.x) >> 4);
    int stride  = ngroups * 2;
    for (int e0 = gid * 2; e0 + 1 < E; e0 += stride) {
        int s0 = edge_index[e0];
        int s1 = edge_index[e0 + 1];
        int d0 = edge_index[E + e0];
        int d1 = edge_index[E + e0 + 1];
        int t0 = edge_type[e0];
        int t1 = edge_type[e0 + 1];
        const uint4* ps0 = reinterpret_cast<const uint4*>(zn + (size_t)s0 * (D / 2)) + l;
        const uint4* pd0 = reinterpret_cast<const uint4*>(zn + (size_t)d0 * (D / 2)) + l;
        const uint4* pc0 = reinterpret_cast<const uint4*>(ct + (size_t)t0 * (D / 2)) + l;
        const uint4* ps1 = reinterpret_cast<const uint4*>(zn + (size_t)s1 * (D / 2)) + l;
        const uint4* pd1 = reinterpret_cast<const uint4*>(zn + (size_t)d1 * (D / 2)) + l;
        const uint4* pc1 = reinterpret_cast<const uint4*>(ct + (size_t)t1 * (D / 2)) + l;
        uint4 sw0 = *ps0, dw0 = *pd0, cw0 = *pc0;
        uint4 sw1 = *ps1, dw1 = *pd1, cw1 = *pc1;
        float p0 = dot8(sw0, cw0, dw0);
        float p1 = dot8(sw1, cw1, dw1);
#pragma unroll
        for (int off = 8; off > 0; off >>= 1) {
            p0 += __shfl_xor(p0, off, 64);
            p1 += __shfl_xor(p1, off, 64);
        }
        if (l == 0) {
            out[e0]     = p0;
            out[e0 + 1] = p1;
        }
    }
    // odd-E tail (not hit for E=640000, kept for generality)
    if ((E & 1) && gid == 0) {
        int e = E - 1;
        int s = edge_index[e], d = edge_index[E + e], t = edge_type[e];
        uint4 sw = reinterpret_cast<const uint4*>(zn + (size_t)s * (D / 2))[l];
        uint4 dw = reinterpret_cast<const uint4*>(zn + (size_t)d * (D / 2))[l];
        uint4 cw = reinterpret_cast<const uint4*>(ct + (size_t)t * (D / 2))[l];
        float p = dot8(sw, cw, dw);
#pragma unroll
        for (int off = 8; off > 0; off >>= 1) p += __shfl_xor(p, off, 64);
        if (l == 0) out[e] = p;
    }
}

extern "C" void kernel_launch(void* const* d_in, const int* in_sizes, int n_in,
                              void* d_out, int out_size, void* d_ws, size_t ws_size,
                              hipStream_t stream) {
    const float* z          = (const float*)d_in[0];
    const int*   edge_index = (const int*)d_in[1];   // [2, E] int32
    const int*   edge_type  = (const int*)d_in[2];   // [E] int32
    const float* phase_rel  = (const float*)d_in[3]; // [R, D]
    float* out = (float*)d_out;

    const int N      = in_sizes[0] / D;
    const int E      = in_sizes[2];
    const int nphase = in_sizes[3]; // R * D

    const size_t zn_bytes = (size_t)N * (D / 2) * sizeof(unsigned int); // 25.6 MB
    const size_t ct_bytes = (size_t)(nphase / 2) * sizeof(unsigned int);

    unsigned int* zn = (unsigned int*)d_ws;
    unsigned int* ct = (unsigned int*)((char*)d_ws + zn_bytes);
    (void)ws_size; (void)ct_bytes;

    // 1) normalized z packed bf16 (2 rows/wave, 8 rows/block)
    norm_pack_kernel<<<(N + 7) / 8, 256, 0, stream>>>(z, zn, N);

    // 2) cos table packed bf16
    const int n2 = nphase / 2;
    cos_pack_kernel<<<(n2 + 255) / 256, 256, 0, stream>>>(phase_rel, ct, n2);

    // 3) edge dots: 2048 blocks * 16 groups * 2 edges in flight
    edge_kernel_v3<<<2048, 256, 0, stream>>>(zn, ct, edge_index, edge_type, out, E);
}

// Round 4
// 62.198 us; speedup vs baseline: 2.1989x; 1.0158x over previous
//
#include <hip/hip_runtime.h>
#include <math.h>

#define D 128
#define EPS_NORM 1e-12f

__device__ __forceinline__ unsigned int f32_to_bf16(float f) {
    unsigned int u = __float_as_uint(f);
    return (u + 0x7FFFu + ((u >> 16) & 1u)) >> 16;
}
__device__ __forceinline__ float bf_lo(unsigned int w) { return __uint_as_float(w << 16); }
__device__ __forceinline__ float bf_hi(unsigned int w) { return __uint_as_float(w & 0xFFFF0000u); }

// 2 rows per wave: lanes 0-31 -> row 2w, lanes 32-63 -> row 2w+1, float4/lane.
__global__ void norm_pack_kernel(const float* __restrict__ z,
                                 unsigned int* __restrict__ zn, int N) {
    int w    = blockIdx.x * (blockDim.x >> 6) + (threadIdx.x >> 6);
    int lane = threadIdx.x & 63;
    int half = lane >> 5;
    int hl   = lane & 31;
    int row  = w * 2 + half;
    if (row >= N) return;
    float4 v = reinterpret_cast<const float4*>(z + (size_t)row * D)[hl];
    float s = v.x * v.x + v.y * v.y + v.z * v.z + v.w * v.w;
#pragma unroll
    for (int off = 16; off > 0; off >>= 1) s += __shfl_xor(s, off, 32);
    float inv = 1.0f / fmaxf(sqrtf(s), EPS_NORM);
    uint2 o;
    o.x = (f32_to_bf16(v.y * inv) << 16) | f32_to_bf16(v.x * inv);
    o.y = (f32_to_bf16(v.w * inv) << 16) | f32_to_bf16(v.z * inv);
    reinterpret_cast<uint2*>(zn + (size_t)row * (D / 2))[hl] = o;
}

// cos of phase table, packed bf16x2 (row-major [R, D/2] uints)
__global__ void cos_pack_kernel(const float* __restrict__ phase,
                                unsigned int* __restrict__ ct, int n2) {
    int i = blockIdx.x * blockDim.x + threadIdx.x;
    if (i < n2) {
        float a = cosf(phase[2 * i]);
        float b = cosf(phase[2 * i + 1]);
        ct[i] = (f32_to_bf16(b) << 16) | f32_to_bf16(a);
    }
}

__device__ __forceinline__ float dot8(uint4 sw, uint4 cw, uint4 dw) {
    float p;
    p = bf_lo(sw.x) * bf_lo(cw.x) * bf_lo(dw.x);
    p = fmaf(bf_hi(sw.x) * bf_hi(cw.x), bf_hi(dw.x), p);
    p = fmaf(bf_lo(sw.y) * bf_lo(cw.y), bf_lo(dw.y), p);
    p = fmaf(bf_hi(sw.y) * bf_hi(cw.y), bf_hi(dw.y), p);
    p = fmaf(bf_lo(sw.z) * bf_lo(cw.z), bf_lo(dw.z), p);
    p = fmaf(bf_hi(sw.z) * bf_hi(cw.z), bf_hi(dw.z), p);
    p = fmaf(bf_lo(sw.w) * bf_lo(cw.w), bf_lo(dw.w), p);
    p = fmaf(bf_hi(sw.w) * bf_hi(cw.w), bf_hi(dw.w), p);
    return p;
}

// 16 lanes per edge, 4 edges in flight per group, index prefetch 1 iter ahead.
__global__ __launch_bounds__(256, 6) void edge_kernel_v4(
    const unsigned int* __restrict__ zn,   // [N, D/2]
    const unsigned int* __restrict__ ct,   // [R, D/2]
    const int* __restrict__ ei,            // [2, E]
    const int* __restrict__ et,            // [E]
    float* __restrict__ out, int E) {
    const uint4* zn4 = reinterpret_cast<const uint4*>(zn); // row = node*16 + l
    const uint4* ct4 = reinterpret_cast<const uint4*>(ct);
    int tid     = (int)(blockIdx.x * blockDim.x + threadIdx.x);
    int gid     = tid >> 4;
    int l       = threadIdx.x & 15;
    int ngroups = (int)((gridDim.x * blockDim.x) >> 4);
    int stride  = ngroups * 4;
    int E4      = E & ~3;

    int e = gid * 4;
    int s0, s1, s2, s3, d0, d1, d2, d3, t0, t1, t2, t3;
    if (e < E4) {
        s0 = ei[e];     s1 = ei[e + 1];     s2 = ei[e + 2];     s3 = ei[e + 3];
        d0 = ei[E + e]; d1 = ei[E + e + 1]; d2 = ei[E + e + 2]; d3 = ei[E + e + 3];
        t0 = et[e];     t1 = et[e + 1];     t2 = et[e + 2];     t3 = et[e + 3];
    }
    for (; e < E4; e += stride) {
        int en = e + stride;
        int ep = (en < E4) ? en : e; // clamp: reload current (harmless) on last iter
        // prefetch next iteration's indices
        int ns0 = ei[ep],     ns1 = ei[ep + 1],     ns2 = ei[ep + 2],     ns3 = ei[ep + 3];
        int nd0 = ei[E + ep], nd1 = ei[E + ep + 1], nd2 = ei[E + ep + 2], nd3 = ei[E + ep + 3];
        int nt0 = et[ep],     nt1 = et[ep + 1],     nt2 = et[ep + 2],     nt3 = et[ep + 3];
        // 12 gathers in flight
        uint4 A0 = zn4[(size_t)s0 * 16 + l];
        uint4 B0 = zn4[(size_t)d0 * 16 + l];
        uint4 C0 = ct4[(size_t)t0 * 16 + l];
        uint4 A1 = zn4[(size_t)s1 * 16 + l];
        uint4 B1 = zn4[(size_t)d1 * 16 + l];
        uint4 C1 = ct4[(size_t)t1 * 16 + l];
        uint4 A2 = zn4[(size_t)s2 * 16 + l];
        uint4 B2 = zn4[(size_t)d2 * 16 + l];
        uint4 C2 = ct4[(size_t)t2 * 16 + l];
        uint4 A3 = zn4[(size_t)s3 * 16 + l];
        uint4 B3 = zn4[(size_t)d3 * 16 + l];
        uint4 C3 = ct4[(size_t)t3 * 16 + l];
        float p0 = dot8(A0, C0, B0);
        float p1 = dot8(A1, C1, B1);
        float p2 = dot8(A2, C2, B2);
        float p3 = dot8(A3, C3, B3);
#pragma unroll
        for (int off = 8; off > 0; off >>= 1) {
            p0 += __shfl_xor(p0, off, 64);
            p1 += __shfl_xor(p1, off, 64);
            p2 += __shfl_xor(p2, off, 64);
            p3 += __shfl_xor(p3, off, 64);
        }
        float v = (l == 0) ? p0 : (l == 1) ? p1 : (l == 2) ? p2 : p3;
        if (l < 4) out[e + l] = v; // one coalesced 16 B store per group
        s0 = ns0; s1 = ns1; s2 = ns2; s3 = ns3;
        d0 = nd0; d1 = nd1; d2 = nd2; d3 = nd3;
        t0 = nt0; t1 = nt1; t2 = nt2; t3 = nt3;
    }
    // tail (E % 4 edges)
    for (int e2 = E4 + gid; e2 < E; e2 += ngroups) {
        int s = ei[e2], dd = ei[E + e2], t = et[e2];
        uint4 A = zn4[(size_t)s * 16 + l];
        uint4 B = zn4[(size_t)dd * 16 + l];
        uint4 C = ct4[(size_t)t * 16 + l];
        float p = dot8(A, C, B);
#pragma unroll
        for (int off = 8; off > 0; off >>= 1) p += __shfl_xor(p, off, 64);
        if (l == 0) out[e2] = p;
    }
}

extern "C" void kernel_launch(void* const* d_in, const int* in_sizes, int n_in,
                              void* d_out, int out_size, void* d_ws, size_t ws_size,
                              hipStream_t stream) {
    const float* z          = (const float*)d_in[0];
    const int*   edge_index = (const int*)d_in[1];   // [2, E] int32
    const int*   edge_type  = (const int*)d_in[2];   // [E] int32
    const float* phase_rel  = (const float*)d_in[3]; // [R, D]
    float* out = (float*)d_out;

    const int N      = in_sizes[0] / D;
    const int E      = in_sizes[2];
    const int nphase = in_sizes[3]; // R * D

    const size_t zn_bytes = (size_t)N * (D / 2) * sizeof(unsigned int); // 25.6 MB

    unsigned int* zn = (unsigned int*)d_ws;
    unsigned int* ct = (unsigned int*)((char*)d_ws + zn_bytes);
    (void)ws_size;

    // 1) normalized z packed bf16 (2 rows/wave, 8 rows/block)
    norm_pack_kernel<<<(N + 7) / 8, 256, 0, stream>>>(z, zn, N);

    // 2) cos table packed bf16
    const int n2 = nphase / 2;
    cos_pack_kernel<<<(n2 + 255) / 256, 256, 0, stream>>>(phase_rel, ct, n2);

    // 3) edge dots: 2048 blocks, 16-lane groups, 4 edges in flight each
    edge_kernel_v4<<<2048, 256, 0, stream>>>(zn, ct, edge_index, edge_type, out, E);
}

// Round 5
// 60.474 us; speedup vs baseline: 2.2616x; 1.0285x over previous
//
#include <hip/hip_runtime.h>
#include <math.h>

#define D 128
#define EPS_NORM 1e-12f

__device__ __forceinline__ unsigned int f32_to_bf16(float f) {
    unsigned int u = __float_as_uint(f);
    return (u + 0x7FFFu + ((u >> 16) & 1u)) >> 16;
}
__device__ __forceinline__ float bf_lo(unsigned int w) { return __uint_as_float(w << 16); }
__device__ __forceinline__ float bf_hi(unsigned int w) { return __uint_as_float(w & 0xFFFF0000u); }

// Fused precompute: blocks [0, nbz) L2-normalize + bf16-pack z (2 rows/wave);
// blocks [nbz, ...) cos-pack the phase table.
__global__ void prep_kernel(const float* __restrict__ z, unsigned int* __restrict__ zn, int N,
                            const float* __restrict__ phase, unsigned int* __restrict__ ct, int n2,
                            int nbz) {
    if ((int)blockIdx.x < nbz) {
        int w    = blockIdx.x * 4 + (threadIdx.x >> 6);
        int lane = threadIdx.x & 63;
        int half = lane >> 5;
        int hl   = lane & 31;
        int row  = w * 2 + half;
        if (row >= N) return;
        float4 v = reinterpret_cast<const float4*>(z + (size_t)row * D)[hl];
        float s = v.x * v.x + v.y * v.y + v.z * v.z + v.w * v.w;
#pragma unroll
        for (int off = 16; off > 0; off >>= 1) s += __shfl_xor(s, off, 32);
        float inv = 1.0f / fmaxf(sqrtf(s), EPS_NORM);
        uint2 o;
        o.x = (f32_to_bf16(v.y * inv) << 16) | f32_to_bf16(v.x * inv);
        o.y = (f32_to_bf16(v.w * inv) << 16) | f32_to_bf16(v.z * inv);
        reinterpret_cast<uint2*>(zn + (size_t)row * (D / 2))[hl] = o;
    } else {
        int i = (blockIdx.x - nbz) * blockDim.x + threadIdx.x;
        if (i < n2) {
            float a = cosf(phase[2 * i]);
            float b = cosf(phase[2 * i + 1]);
            ct[i] = (f32_to_bf16(b) << 16) | f32_to_bf16(a);
        }
    }
}

__device__ __forceinline__ float dot8(uint4 sw, uint4 cw, uint4 dw) {
    float p;
    p = bf_lo(sw.x) * bf_lo(cw.x) * bf_lo(dw.x);
    p = fmaf(bf_hi(sw.x) * bf_hi(cw.x), bf_hi(dw.x), p);
    p = fmaf(bf_lo(sw.y) * bf_lo(cw.y), bf_lo(dw.y), p);
    p = fmaf(bf_hi(sw.y) * bf_hi(cw.y), bf_hi(dw.y), p);
    p = fmaf(bf_lo(sw.z) * bf_lo(cw.z), bf_lo(dw.z), p);
    p = fmaf(bf_hi(sw.z) * bf_hi(cw.z), bf_hi(dw.z), p);
    p = fmaf(bf_lo(sw.w) * bf_lo(cw.w), bf_lo(dw.w), p);
    p = fmaf(bf_hi(sw.w) * bf_hi(cw.w), bf_hi(dw.w), p);
    return p;
}

// Issue all loads for 4 edges of stage S (3 int4 index loads + 12 uint4 gathers)
#define ISSUE(S, ev)                                                      \
    int4 S##s = *reinterpret_cast<const int4*>(ei + (ev));                \
    int4 S##d = *reinterpret_cast<const int4*>(ei + E + (ev));            \
    int4 S##t = *reinterpret_cast<const int4*>(et + (ev));                \
    uint4 S##A0 = zn4[(size_t)S##s.x * 16 + l];                           \
    uint4 S##B0 = zn4[(size_t)S##d.x * 16 + l];                           \
    uint4 S##C0 = ct4[(size_t)S##t.x * 16 + l];                           \
    uint4 S##A1 = zn4[(size_t)S##s.y * 16 + l];                           \
    uint4 S##B1 = zn4[(size_t)S##d.y * 16 + l];                           \
    uint4 S##C1 = ct4[(size_t)S##t.y * 16 + l];                           \
    uint4 S##A2 = zn4[(size_t)S##s.z * 16 + l];                           \
    uint4 S##B2 = zn4[(size_t)S##d.z * 16 + l];                           \
    uint4 S##C2 = ct4[(size_t)S##t.z * 16 + l];                           \
    uint4 S##A3 = zn4[(size_t)S##s.w * 16 + l];                           \
    uint4 S##B3 = zn4[(size_t)S##d.w * 16 + l];                           \
    uint4 S##C3 = ct4[(size_t)S##t.w * 16 + l];

#define COMPUTE(S, ebase)                                                 \
    {                                                                     \
        float p0 = dot8(S##A0, S##C0, S##B0);                             \
        float p1 = dot8(S##A1, S##C1, S##B1);                             \
        float p2 = dot8(S##A2, S##C2, S##B2);                             \
        float p3 = dot8(S##A3, S##C3, S##B3);                             \
        _Pragma("unroll")                                                 \
        for (int off = 8; off > 0; off >>= 1) {                           \
            p0 += __shfl_xor(p0, off, 64);                                \
            p1 += __shfl_xor(p1, off, 64);                                \
            p2 += __shfl_xor(p2, off, 64);                                \
            p3 += __shfl_xor(p3, off, 64);                                \
        }                                                                 \
        float v = (l == 0) ? p0 : (l == 1) ? p1 : (l == 2) ? p2 : p3;     \
        if (l < 4) out[(ebase) + l] = v;                                  \
    }

// 16 lanes/edge, 8 edges per group-iteration, ALL 30 loads issued before
// any compute (asm memory fence prevents load sinking).
__global__ __launch_bounds__(256, 4) void edge_kernel_v5(
    const unsigned int* __restrict__ zn,   // [N, D/2]
    const unsigned int* __restrict__ ct,   // [R, D/2]
    const int* __restrict__ ei,            // [2, E]
    const int* __restrict__ et,            // [E]
    float* __restrict__ out, int E) {
    const uint4* zn4 = reinterpret_cast<const uint4*>(zn); // row = node*16 + l
    const uint4* ct4 = reinterpret_cast<const uint4*>(ct);
    int tid     = (int)(blockIdx.x * blockDim.x + threadIdx.x);
    int gid     = tid >> 4;
    int l       = threadIdx.x & 15;
    int ngroups = (int)((gridDim.x * blockDim.x) >> 4);
    int stride  = ngroups * 8;
    int E8      = E & ~7;

    for (int e = gid * 8; e + 8 <= E8; e += stride) {
        ISSUE(P, e)
        ISSUE(Q, e + 4)
        asm volatile("" ::: "memory"); // loads above cannot sink below
        COMPUTE(P, e)
        COMPUTE(Q, e + 4)
    }
    // tail (E % 8 edges)
    for (int e2 = E8 + gid; e2 < E; e2 += ngroups) {
        int s = ei[e2], dd = ei[E + e2], t = et[e2];
        uint4 A = zn4[(size_t)s * 16 + l];
        uint4 B = zn4[(size_t)dd * 16 + l];
        uint4 C = ct4[(size_t)t * 16 + l];
        float p = dot8(A, C, B);
#pragma unroll
        for (int off = 8; off > 0; off >>= 1) p += __shfl_xor(p, off, 64);
        if (l == 0) out[e2] = p;
    }
}

extern "C" void kernel_launch(void* const* d_in, const int* in_sizes, int n_in,
                              void* d_out, int out_size, void* d_ws, size_t ws_size,
                              hipStream_t stream) {
    const float* z          = (const float*)d_in[0];
    const int*   edge_index = (const int*)d_in[1];   // [2, E] int32
    const int*   edge_type  = (const int*)d_in[2];   // [E] int32
    const float* phase_rel  = (const float*)d_in[3]; // [R, D]
    float* out = (float*)d_out;

    const int N      = in_sizes[0] / D;
    const int E      = in_sizes[2];
    const int nphase = in_sizes[3]; // R * D

    const size_t zn_bytes = (size_t)N * (D / 2) * sizeof(unsigned int); // 25.6 MB

    unsigned int* zn = (unsigned int*)d_ws;
    unsigned int* ct = (unsigned int*)((char*)d_ws + zn_bytes);
    (void)ws_size;

    // 1) fused precompute: norm+pack z, cos+pack phase
    const int n2  = nphase / 2;
    const int nbz = (N + 7) / 8;
    const int nbc = (n2 + 255) / 256;
    prep_kernel<<<nbz + nbc, 256, 0, stream>>>(z, zn, N, phase_rel, ct, n2, nbz);

    // 2) edge dots: 2048 blocks, 16-lane groups, 8 edges (30 loads) in flight each
    edge_kernel_v5<<<2048, 256, 0, stream>>>(zn, ct, edge_index, edge_type, out, E);
}